// Round 1
// baseline (886.895 us; speedup 1.0000x reference)
//
#include <hip/hip_runtime.h>
#include <stdint.h>

#define NCLS  21
#define CDIM  256
#define HWSZ  16384
#define NPIX  131072
#define EPSV  1e-6f
#define NEGV  -1e30f
#define CAP_W 4096
#define CAP_S 16384
#define KSEL  256

__device__ __forceinline__ uint64_t pack_key(float v, unsigned idx) {
  unsigned u = __float_as_uint(v);
  u = (u & 0x80000000u) ? ~u : (u | 0x80000000u);  // ascending order map
  return ((uint64_t)(~u) << 32) | (uint64_t)idx;   // ascending key == descending value, tie -> low idx
}

// ---------------- K0: normalize prototypes, zero accumulators ----------------
__global__ void k0_init(const float* __restrict__ mb, float* pn, float* wsum,
                        int* wcnt, int* scnt) {
  int k = blockIdx.x, t = threadIdx.x;
  float v = mb[k * CDIM + t];
  float s = v * v;
  for (int o = 32; o > 0; o >>= 1) s += __shfl_down(s, o, 64);
  __shared__ float wsh[4];
  int wid = t >> 6, lane = t & 63;
  if (lane == 0) wsh[wid] = s;
  __syncthreads();
  float tot = wsh[0] + wsh[1] + wsh[2] + wsh[3];
  float inv = 1.0f / fmaxf(sqrtf(tot), EPSV);
  pn[k * CDIM + t] = v * inv;
  wsum[k * CDIM + t] = 0.0f;
  if (t == 0) { wcnt[k] = 0; scnt[k] = 0; }
}

// ---------------- K1: per-pixel sims + candidate compaction + wsum ----------------
__global__ void k1_main(const float* __restrict__ fw, const float* __restrict__ fs,
                        const float* __restrict__ prob, const int* __restrict__ seg,
                        const int* __restrict__ ign, const float* __restrict__ pn,
                        float* wsum, int* wcnt, int* scnt,
                        uint64_t* wkeys, uint64_t* skeys) {
  __shared__ float pnT[CDIM * NCLS];  // [c][k] layout: conflict-free across lanes
  int t = threadIdx.x;
  for (int idx = t; idx < NCLS * CDIM; idx += 256) {
    int k = idx >> 8, c = idx & 255;
    pnT[c * NCLS + k] = pn[idx];
  }
  __syncthreads();
  int n = blockIdx.x * 256 + t;
  int b = n >> 14, hw = n & (HWSZ - 1);
  bool valid = (ign[n] != 255);
  if (!valid) return;
  int k = seg[n];
  bool conf = (prob[n] > 0.95f);
  const float* fwp = fw + (size_t)b * CDIM * HWSZ + hw;
  const float* fsp = fs + (size_t)b * CDIM * HWSZ + hw;
  float dw = 0.f, nw = 0.f, ds = 0.f, ns = 0.f;
#pragma unroll 8
  for (int c = 0; c < CDIM; ++c) {
    float a  = fwp[(size_t)c * HWSZ];
    float s2 = fsp[(size_t)c * HWSZ];
    float p  = pnT[c * NCLS + k];
    dw = fmaf(a, p, dw);  nw = fmaf(a, a, nw);
    ds = fmaf(s2, p, ds); ns = fmaf(s2, s2, ns);
    if (conf) atomicAdd(&wsum[k * CDIM + c], a);
  }
  float sim_s = ds / fmaxf(sqrtf(ns), EPSV);
  int pos = atomicAdd(&scnt[k], 1);
  if (pos < CAP_S) skeys[(size_t)k * CAP_S + pos] = pack_key(-sim_s, (unsigned)n);
  if (conf) {
    float sim_w = dw / fmaxf(sqrtf(nw), EPSV);
    int pos2 = atomicAdd(&wcnt[k], 1);
    if (pos2 < CAP_W) wkeys[(size_t)k * CAP_W + pos2] = pack_key(sim_w, (unsigned)n);
  }
}

// ---------------- K2: per-class top-k (cutoff-filtered bitonic) ----------------
__global__ void k2_topk(const uint64_t* __restrict__ wkeys, const uint64_t* __restrict__ skeys,
                        const int* wcnt, const int* scnt,
                        int* idxw, int* idxs, int* kwv, int* ksv, int* nwv, int* nsv) {
  int bid = blockIdx.x;
  bool strong = bid < NCLS;
  int k = strong ? bid : bid - NCLS;
  const uint64_t* list = strong ? (skeys + (size_t)k * CAP_S) : (wkeys + (size_t)k * CAP_W);
  int cnt_total = strong ? scnt[k] : wcnt[k];
  int cap = strong ? CAP_S : CAP_W;
  int cnt = cnt_total < cap ? cnt_total : cap;
  int t = threadIdx.x;
  __shared__ uint64_t T[KSEL];
  __shared__ uint64_t P[2 * KSEL];
  __shared__ int pcnt_s;
  __shared__ int woff_s[4];
  T[t] = ~0ull;
  if (t == 0) pcnt_s = 0;
  __syncthreads();
  for (int base = 0; base < cnt; base += 256) {
    uint64_t key = (base + t < cnt) ? list[base + t] : ~0ull;
    uint64_t cutoff = T[KSEL - 1];
    bool pred = key < cutoff;
    unsigned long long mask = __ballot(pred);
    int wid = t >> 6, lane = t & 63;
    if (lane == 0) woff_s[wid] = __popcll(mask);
    int prefix = __popcll(mask & ((1ull << lane) - 1ull));
    __syncthreads();
    int off = 0;
    for (int w2 = 0; w2 < wid; ++w2) off += woff_s[w2];
    int total = woff_s[0] + woff_s[1] + woff_s[2] + woff_s[3];
    int old = pcnt_s;
    if (pred) P[old + off + prefix] = key;
    int newc = old + total;
    __syncthreads();
    if (t == 0) pcnt_s = newc;
    bool last = (base + 256 >= cnt);
    if (newc >= KSEL || (last && newc > 0)) {
      for (int i2 = t; i2 < 2 * KSEL; i2 += 256)
        if (i2 >= newc) P[i2] = ~0ull;
      // bitonic sort P[0..511] ascending (256 threads, 1 pair each per stage)
      for (unsigned size = 2; size <= 2 * KSEL; size <<= 1) {
        for (unsigned stride = size >> 1; stride > 0; stride >>= 1) {
          __syncthreads();
          unsigned lo = stride - 1;
          unsigned i = (((unsigned)t & ~lo) << 1) | ((unsigned)t & lo);
          unsigned j = i | stride;
          uint64_t a = P[i], b = P[j];
          bool up = ((i & size) == 0);
          if ((a > b) == up) { P[i] = b; P[j] = a; }
        }
      }
      __syncthreads();
      // keep K smallest of T ∪ P[0..255]: min-merge then bitonic merge
      {
        uint64_t a = T[t], b = P[KSEL - 1 - t];
        T[t] = a < b ? a : b;
      }
      for (unsigned stride = KSEL / 2; stride > 0; stride >>= 1) {
        __syncthreads();
        if (((unsigned)t & stride) == 0) {
          uint64_t x = T[t], y = T[t + stride];
          if (x > y) { T[t] = y; T[t + stride] = x; }
        }
      }
      if (t == 0) pcnt_s = 0;
      __syncthreads();
    } else {
      __syncthreads();
    }
  }
  if (strong) {
    idxs[k * KSEL + t] = (int)(unsigned)(T[t] & 0xFFFFFFFFull);
    if (t == 0) { nsv[k] = cnt_total; ksv[k] = cnt_total < KSEL ? cnt_total : KSEL; }
  } else {
    if (t < 16) idxw[k * 16 + t] = (int)(unsigned)(T[t] & 0xFFFFFFFFull);
    if (t == 0) { nwv[k] = cnt_total; kwv[k] = cnt_total < 16 ? cnt_total : 16; }
  }
}

// ---------------- K3a: gather + normalize selected vectors into dense buffers ----------------
__global__ void k3a_gather(const float* __restrict__ fw, const float* __restrict__ fs,
                           const int* __restrict__ idxw, const int* __restrict__ idxs,
                           const int* __restrict__ kwv, const int* __restrict__ ksv,
                           float* dw_dense, float* ds_dense) {
  int k = blockIdx.y;
  int slot = blockIdx.x;  // 0..255 strong, 256..271 weak
  int t = threadIdx.x;
  bool strong = slot < KSEL;
  float v = 0.0f;
  int n = 0;
  bool ok;
  if (strong) {
    ok = slot < ksv[k];
    if (ok) n = idxs[k * KSEL + slot];
  } else {
    int i = slot - KSEL;
    ok = i < kwv[k];
    int rank = i > 0 ? i - 1 : 0;  // ranks = max(arange(16)-1, 0)
    if (ok) n = idxw[k * 16 + rank];
  }
  if (ok) {
    int b = n >> 14, hw = n & (HWSZ - 1);
    const float* f = strong ? fs : fw;
    v = f[(size_t)(b * CDIM + t) * HWSZ + hw];
  }
  float s = v * v;
  for (int o = 32; o > 0; o >>= 1) s += __shfl_down(s, o, 64);
  __shared__ float wsh[4];
  int wid = t >> 6, lane = t & 63;
  if (lane == 0) wsh[wid] = s;
  __syncthreads();
  float tot = wsh[0] + wsh[1] + wsh[2] + wsh[3];
  float inv = 1.0f / fmaxf(sqrtf(tot), EPSV);
  float out = v * inv;
  if (strong) ds_dense[((size_t)k * KSEL + slot) * CDIM + t] = out;
  else        dw_dense[((size_t)k * 16 + (slot - KSEL)) * CDIM + t] = out;
}

// ---------------- K3b: cosm, per-row max, per-class sum ----------------
__global__ void k3b_loss(const float* __restrict__ dw_dense, const float* __restrict__ ds_dense,
                         const int* kwv, const int* ksv, const int* nwv, const int* nsv,
                         float* simsum, int* countk) {
  int k = blockIdx.x, t = threadIdx.x;
  __shared__ float wn[16 * CDIM];
  __shared__ float red[256];
  for (int i = t; i < 16 * CDIM; i += 256) wn[i] = dw_dense[(size_t)k * 16 * CDIM + i];
  __syncthreads();
  int ks_ = ksv[k], kw_ = kwv[k];
  bool ok = (nwv[k] > 0) && (nsv[k] > 0);
  float dots[16];
#pragma unroll
  for (int i = 0; i < 16; ++i) dots[i] = 0.0f;
  bool jv = ok && (t < ks_);
  if (jv) {
    const float4* sp = (const float4*)(ds_dense + ((size_t)k * KSEL + t) * CDIM);
    for (int c4 = 0; c4 < CDIM / 4; ++c4) {
      float4 v = sp[c4];
#pragma unroll
      for (int i = 0; i < 16; ++i) {
        float4 w = ((const float4*)(wn + i * CDIM))[c4];
        dots[i] = fmaf(v.x, w.x, dots[i]);
        dots[i] = fmaf(v.y, w.y, dots[i]);
        dots[i] = fmaf(v.z, w.z, dots[i]);
        dots[i] = fmaf(v.w, w.w, dots[i]);
      }
    }
  }
  float csum = 0.0f;
  for (int i = 0; i < 16; ++i) {
    red[t] = jv ? dots[i] : NEGV;
    __syncthreads();
    for (int s2 = 128; s2 > 0; s2 >>= 1) {
      if (t < s2) red[t] = fmaxf(red[t], red[t + s2]);
      __syncthreads();
    }
    if (t == 0 && i < kw_) csum += red[0];
    __syncthreads();
  }
  if (t == 0) { simsum[k] = ok ? csum : 0.0f; countk[k] = ok ? ks_ : 0; }
}

// ---------------- K4: memory bank update + loss ----------------
__global__ void k4_final(const float* __restrict__ mb, const float* __restrict__ wsum,
                         const int* __restrict__ nwv, const float* __restrict__ simsum,
                         const int* __restrict__ countk, float* out) {
  int k = blockIdx.x, t = threadIdx.x;
  float p = mb[k * CDIM + t];
  float o = p;
  int nw = nwv[k];
  if (nw > 0) {
    float mean = wsum[k * CDIM + t] / (float)nw;
    o = 0.99f * p + 0.01f * mean;
  }
  out[1 + k * CDIM + t] = o;
  if (k == 0 && t == 0) {
    float ss = 0.0f;
    int cc = 0;
    for (int q = 0; q < NCLS; ++q) { ss += simsum[q]; cc += countk[q]; }
    out[0] = (cc > 0) ? (1.0f - ss / (float)cc) : 0.0f;
  }
}

extern "C" void kernel_launch(void* const* d_in, const int* in_sizes, int n_in,
                              void* d_out, int out_size, void* d_ws, size_t ws_size,
                              hipStream_t stream) {
  const float* fw   = (const float*)d_in[0];
  const float* fs   = (const float*)d_in[1];
  const float* prob = (const float*)d_in[2];
  const float* mb   = (const float*)d_in[3];
  const int*   seg  = (const int*)d_in[4];
  const int*   ign  = (const int*)d_in[5];
  float* out = (float*)d_out;

  char* ws = (char*)d_ws;
  size_t off = 0;
  auto alloc = [&](size_t bytes) -> char* {
    char* p = ws + off;
    off = (off + bytes + 255) & ~(size_t)255;
    return p;
  };
  float*    pn       = (float*)alloc(NCLS * CDIM * 4);
  float*    wsum     = (float*)alloc(NCLS * CDIM * 4);
  int*      wcnt     = (int*)alloc(NCLS * 4);
  int*      scnt     = (int*)alloc(NCLS * 4);
  int*      idxw     = (int*)alloc(NCLS * 16 * 4);
  int*      idxs     = (int*)alloc(NCLS * KSEL * 4);
  int*      kwv      = (int*)alloc(NCLS * 4);
  int*      ksv      = (int*)alloc(NCLS * 4);
  int*      nwv      = (int*)alloc(NCLS * 4);
  int*      nsv      = (int*)alloc(NCLS * 4);
  float*    simsum   = (float*)alloc(NCLS * 4);
  int*      countk   = (int*)alloc(NCLS * 4);
  uint64_t* wkeys    = (uint64_t*)alloc((size_t)NCLS * CAP_W * 8);
  uint64_t* skeys    = (uint64_t*)alloc((size_t)NCLS * CAP_S * 8);
  float*    dw_dense = (float*)alloc((size_t)NCLS * 16 * CDIM * 4);
  float*    ds_dense = (float*)alloc((size_t)NCLS * KSEL * CDIM * 4);
  (void)in_sizes; (void)n_in; (void)out_size; (void)ws_size;

  k0_init<<<NCLS, 256, 0, stream>>>(mb, pn, wsum, wcnt, scnt);
  k1_main<<<NPIX / 256, 256, 0, stream>>>(fw, fs, prob, seg, ign, pn,
                                          wsum, wcnt, scnt, wkeys, skeys);
  k2_topk<<<2 * NCLS, 256, 0, stream>>>(wkeys, skeys, wcnt, scnt,
                                        idxw, idxs, kwv, ksv, nwv, nsv);
  k3a_gather<<<dim3(KSEL + 16, NCLS), 256, 0, stream>>>(fw, fs, idxw, idxs, kwv, ksv,
                                                        dw_dense, ds_dense);
  k3b_loss<<<NCLS, 256, 0, stream>>>(dw_dense, ds_dense, kwv, ksv, nwv, nsv,
                                     simsum, countk);
  k4_final<<<NCLS, 256, 0, stream>>>(mb, wsum, nwv, simsum, countk, out);
}

// Round 2
// 864.390 us; speedup vs baseline: 1.0260x; 1.0260x over previous
//
#include <hip/hip_runtime.h>
#include <stdint.h>

#define NCLS  21
#define CDIM  256
#define HWSZ  16384
#define NPIX  131072
#define EPSV  1e-6f
#define NEGV  -1e30f
#define CAP_W 4096
#define CAP_S 16384
#define KSEL  256
#define NCC   8            // channel chunks in k1a
#define CCH   (CDIM/NCC)   // 32 channels per chunk
#define NPART 8            // strong top-k partitions per class

__device__ __forceinline__ uint64_t pack_key(float v, unsigned idx) {
  unsigned u = __float_as_uint(v);
  u = (u & 0x80000000u) ? ~u : (u | 0x80000000u);  // order-preserving map
  return ((uint64_t)(~u) << 32) | (uint64_t)idx;   // ascending key == descending value, tie -> low idx
}

// ---------------- K0: normalize prototypes, zero accumulators ----------------
__global__ void k0_init(const float* __restrict__ mb, float* pn, float* wsum,
                        int* wcnt, int* scnt) {
  int k = blockIdx.x, t = threadIdx.x;
  float v = mb[k * CDIM + t];
  float s = v * v;
  for (int o = 32; o > 0; o >>= 1) s += __shfl_down(s, o, 64);
  __shared__ float wsh[4];
  int wid = t >> 6, lane = t & 63;
  if (lane == 0) wsh[wid] = s;
  __syncthreads();
  float tot = wsh[0] + wsh[1] + wsh[2] + wsh[3];
  float inv = 1.0f / fmaxf(sqrtf(tot), EPSV);
  pn[k * CDIM + t] = v * inv;
  wsum[k * CDIM + t] = 0.0f;
  if (t == 0) { wcnt[k] = 0; scnt[k] = 0; }
}

// ---------------- K1a: streaming pass — float4 loads, partial dots, LDS wsum ----------------
// grid: (NPIX/1024, NCC). Each thread: 4 pixels, CCH channels.
__global__ void k1a_stream(const float* __restrict__ fw, const float* __restrict__ fs,
                           const float* __restrict__ prob, const int* __restrict__ seg,
                           const int* __restrict__ ign, const float* __restrict__ pn,
                           float* part, float* wsum) {
  __shared__ float pnT[CCH * NCLS];          // [c_local][k]
  __shared__ float wloc[NCLS * (CCH + 1)];   // [k][c_local], pad to break bank aliasing
  int t = threadIdx.x;
  int pg = blockIdx.x;   // pixel group (1024 pixels)
  int cc = blockIdx.y;   // channel chunk
  int c0 = cc * CCH;
  for (int i = t; i < CCH * NCLS; i += 256) {
    int c = i / NCLS, k = i % NCLS;
    pnT[i] = pn[k * CDIM + c0 + c];
  }
  for (int i = t; i < NCLS * (CCH + 1); i += 256) wloc[i] = 0.0f;
  __syncthreads();

  int n0 = pg * 1024 + t * 4;
  int b = n0 >> 14, hw = n0 & (HWSZ - 1);
  int4   sg = *(const int4*)(seg + n0);
  int4   ig = *(const int4*)(ign + n0);
  float4 pr = *(const float4*)(prob + n0);
  bool cf0 = (ig.x != 255) && (pr.x > 0.95f);
  bool cf1 = (ig.y != 255) && (pr.y > 0.95f);
  bool cf2 = (ig.z != 255) && (pr.z > 0.95f);
  bool cf3 = (ig.w != 255) && (pr.w > 0.95f);

  const float* fwp = fw + ((size_t)b * CDIM + c0) * HWSZ + hw;
  const float* fsp = fs + ((size_t)b * CDIM + c0) * HWSZ + hw;

  float4 dw = {0,0,0,0}, nw = {0,0,0,0}, dsv = {0,0,0,0}, ns = {0,0,0,0};
#pragma unroll 4
  for (int cl = 0; cl < CCH; ++cl) {
    float4 a = *(const float4*)(fwp + (size_t)cl * HWSZ);
    float4 s = *(const float4*)(fsp + (size_t)cl * HWSZ);
    float p0 = pnT[cl * NCLS + sg.x];
    float p1 = pnT[cl * NCLS + sg.y];
    float p2 = pnT[cl * NCLS + sg.z];
    float p3 = pnT[cl * NCLS + sg.w];
    dw.x = fmaf(a.x, p0, dw.x); nw.x = fmaf(a.x, a.x, nw.x);
    dw.y = fmaf(a.y, p1, dw.y); nw.y = fmaf(a.y, a.y, nw.y);
    dw.z = fmaf(a.z, p2, dw.z); nw.z = fmaf(a.z, a.z, nw.z);
    dw.w = fmaf(a.w, p3, dw.w); nw.w = fmaf(a.w, a.w, nw.w);
    dsv.x = fmaf(s.x, p0, dsv.x); ns.x = fmaf(s.x, s.x, ns.x);
    dsv.y = fmaf(s.y, p1, dsv.y); ns.y = fmaf(s.y, s.y, ns.y);
    dsv.z = fmaf(s.z, p2, dsv.z); ns.z = fmaf(s.z, s.z, ns.z);
    dsv.w = fmaf(s.w, p3, dsv.w); ns.w = fmaf(s.w, s.w, ns.w);
    if (cf0) atomicAdd(&wloc[sg.x * (CCH + 1) + cl], a.x);
    if (cf1) atomicAdd(&wloc[sg.y * (CCH + 1) + cl], a.y);
    if (cf2) atomicAdd(&wloc[sg.z * (CCH + 1) + cl], a.z);
    if (cf3) atomicAdd(&wloc[sg.w * (CCH + 1) + cl], a.w);
  }
  float4* pp = (float4*)part + ((size_t)cc * NPIX + n0);
  pp[0] = make_float4(dw.x, nw.x, dsv.x, ns.x);
  pp[1] = make_float4(dw.y, nw.y, dsv.y, ns.y);
  pp[2] = make_float4(dw.z, nw.z, dsv.z, ns.z);
  pp[3] = make_float4(dw.w, nw.w, dsv.w, ns.w);

  __syncthreads();
  for (int i = t; i < NCLS * CCH; i += 256) {
    int k = i / CCH, cl = i % CCH;
    float v = wloc[k * (CCH + 1) + cl];
    if (v != 0.0f) atomicAdd(&wsum[k * CDIM + c0 + cl], v);
  }
}

// ---------------- K1b: combine partials, compute sims, wave-aggregated compaction ----------------
__global__ void k1b_combine(const float* __restrict__ part, const float* __restrict__ prob,
                            const int* __restrict__ seg, const int* __restrict__ ign,
                            int* wcnt, int* scnt, uint64_t* wkeys, uint64_t* skeys) {
  int n = blockIdx.x * 256 + threadIdx.x;
  int lane = threadIdx.x & 63;
  bool validv = (ign[n] != 255);
  int kk = seg[n];
  float dw = 0.f, nw = 0.f, ds = 0.f, ns = 0.f;
  if (validv) {
#pragma unroll
    for (int cc = 0; cc < NCC; ++cc) {
      float4 v = *(const float4*)(part + ((size_t)cc * NPIX + n) * 4);
      dw += v.x; nw += v.y; ds += v.z; ns += v.w;
    }
  }
  float sim_s = ds / fmaxf(sqrtf(ns), EPSV);
  float sim_w = dw / fmaxf(sqrtf(nw), EPSV);
  bool conf = validv && (prob[n] > 0.95f);
  for (int q = 0; q < NCLS; ++q) {
    unsigned long long ms = __ballot(validv && (kk == q));
    if (ms) {
      int base = 0;
      int leader = __ffsll((long long)ms) - 1;
      if (lane == leader) base = atomicAdd(&scnt[q], __popcll(ms));
      base = __shfl(base, leader, 64);
      if (validv && (kk == q)) {
        int pos = base + __popcll(ms & ((1ull << lane) - 1ull));
        if (pos < CAP_S) skeys[(size_t)q * CAP_S + pos] = pack_key(-sim_s, (unsigned)n);
      }
    }
    unsigned long long mw = __ballot(conf && (kk == q));
    if (mw) {
      int base = 0;
      int leader = __ffsll((long long)mw) - 1;
      if (lane == leader) base = atomicAdd(&wcnt[q], __popcll(mw));
      base = __shfl(base, leader, 64);
      if (conf && (kk == q)) {
        int pos = base + __popcll(mw & ((1ull << lane) - 1ull));
        if (pos < CAP_W) wkeys[(size_t)q * CAP_W + pos] = pack_key(sim_w, (unsigned)n);
      }
    }
  }
}

// ---------------- top-256 select (cutoff-filtered bitonic), 256 threads ----------------
__device__ void select_topk(const uint64_t* __restrict__ list, int cnt,
                            uint64_t* T, uint64_t* P, int* pcnt, int* woff) {
  int t = threadIdx.x;
  T[t] = ~0ull;
  if (t == 0) *pcnt = 0;
  __syncthreads();
  for (int base = 0; base < cnt; base += 256) {
    uint64_t key = (base + t < cnt) ? list[base + t] : ~0ull;
    uint64_t cutoff = T[KSEL - 1];
    bool pred = key < cutoff;
    unsigned long long mask = __ballot(pred);
    int wid = t >> 6, lane = t & 63;
    if (lane == 0) woff[wid] = __popcll(mask);
    int prefix = __popcll(mask & ((1ull << lane) - 1ull));
    __syncthreads();
    int off = 0;
    for (int w2 = 0; w2 < wid; ++w2) off += woff[w2];
    int total = woff[0] + woff[1] + woff[2] + woff[3];
    int old = *pcnt;
    if (pred) P[old + off + prefix] = key;
    int newc = old + total;
    __syncthreads();
    if (t == 0) *pcnt = newc;
    bool last = (base + 256 >= cnt);
    if (newc >= KSEL || (last && newc > 0)) {
      for (int i2 = t; i2 < 2 * KSEL; i2 += 256)
        if (i2 >= newc) P[i2] = ~0ull;
      for (unsigned size = 2; size <= 2 * KSEL; size <<= 1) {
        for (unsigned stride = size >> 1; stride > 0; stride >>= 1) {
          __syncthreads();
          unsigned lo = stride - 1;
          unsigned i = (((unsigned)t & ~lo) << 1) | ((unsigned)t & lo);
          unsigned j = i | stride;
          uint64_t a = P[i], b = P[j];
          bool up = ((i & size) == 0);
          if ((a > b) == up) { P[i] = b; P[j] = a; }
        }
      }
      __syncthreads();
      uint64_t a = T[t], b = P[KSEL - 1 - t];
      T[t] = a < b ? a : b;
      for (unsigned stride = KSEL / 2; stride > 0; stride >>= 1) {
        __syncthreads();
        if (((unsigned)t & stride) == 0) {
          uint64_t x = T[t], y = T[t + stride];
          if (x > y) { T[t] = y; T[t + stride] = x; }
        }
      }
      __syncthreads();
      if (t == 0) *pcnt = 0;
      __syncthreads();
    } else {
      __syncthreads();
    }
  }
}

// ---------------- K2: weak top-16 (full) + strong top-256 (partitioned) ----------------
__global__ void k2_topk(const uint64_t* __restrict__ wkeys, const uint64_t* __restrict__ skeys,
                        const int* wcnt, const int* scnt,
                        uint64_t* psel, int* idxw, int* kwv, int* nwv) {
  __shared__ uint64_t T[KSEL];
  __shared__ uint64_t P[2 * KSEL];
  __shared__ int pcnt;
  __shared__ int woff[4];
  int bid = blockIdx.x, t = threadIdx.x;
  if (bid < NCLS * NPART) {
    int k = bid / NPART, p = bid % NPART;
    int cnt = min(scnt[k], CAP_S);
    int chunk = (cnt + NPART - 1) / NPART;
    int lo = p * chunk;
    int hi = min(lo + chunk, cnt);
    int c = hi > lo ? hi - lo : 0;
    select_topk(skeys + (size_t)k * CAP_S + lo, c, T, P, &pcnt, woff);
    psel[((size_t)k * NPART + p) * KSEL + t] = T[t];
  } else {
    int k = bid - NCLS * NPART;
    int cnt_total = wcnt[k];
    int cnt = min(cnt_total, CAP_W);
    select_topk(wkeys + (size_t)k * CAP_W, cnt, T, P, &pcnt, woff);
    if (t < 16) idxw[k * 16 + t] = (int)(unsigned)(T[t] & 0xFFFFFFFFull);
    if (t == 0) { nwv[k] = cnt_total; kwv[k] = min(cnt_total, 16); }
  }
}

// ---------------- K2m: merge 8 sorted partition results -> final strong top-256 ----------------
__global__ void k2m_merge(const uint64_t* __restrict__ psel, const int* scnt,
                          int* idxs, int* ksv, int* nsv) {
  int k = blockIdx.x, t = threadIdx.x;
  __shared__ uint64_t M[NPART * KSEL];  // 2048
  for (int i = t; i < NPART * KSEL; i += 256) M[i] = psel[(size_t)k * NPART * KSEL + i];
  for (unsigned size = 2; size <= NPART * KSEL; size <<= 1) {
    for (unsigned stride = size >> 1; stride > 0; stride >>= 1) {
      __syncthreads();
      for (unsigned q = t; q < NPART * KSEL / 2; q += 256) {
        unsigned lo = stride - 1;
        unsigned i = ((q & ~lo) << 1) | (q & lo);
        unsigned j = i | stride;
        uint64_t a = M[i], b = M[j];
        bool up = ((i & size) == 0);
        if ((a > b) == up) { M[i] = b; M[j] = a; }
      }
    }
  }
  __syncthreads();
  idxs[k * KSEL + t] = (int)(unsigned)(M[t] & 0xFFFFFFFFull);
  if (t == 0) { int c = scnt[k]; nsv[k] = c; ksv[k] = c < KSEL ? c : KSEL; }
}

// ---------------- K3a: gather + normalize selected vectors into dense buffers ----------------
__global__ void k3a_gather(const float* __restrict__ fw, const float* __restrict__ fs,
                           const int* __restrict__ idxw, const int* __restrict__ idxs,
                           const int* __restrict__ kwv, const int* __restrict__ ksv,
                           float* dw_dense, float* ds_dense) {
  int k = blockIdx.y;
  int slot = blockIdx.x;  // 0..255 strong, 256..271 weak
  int t = threadIdx.x;
  bool strong = slot < KSEL;
  float v = 0.0f;
  int n = 0;
  bool ok;
  if (strong) {
    ok = slot < ksv[k];
    if (ok) n = idxs[k * KSEL + slot];
  } else {
    int i = slot - KSEL;
    ok = i < kwv[k];
    int rank = i > 0 ? i - 1 : 0;  // ranks = max(arange(16)-1, 0)
    if (ok) n = idxw[k * 16 + rank];
  }
  if (ok) {
    int b = n >> 14, hw = n & (HWSZ - 1);
    const float* f = strong ? fs : fw;
    v = f[(size_t)(b * CDIM + t) * HWSZ + hw];
  }
  float s = v * v;
  for (int o = 32; o > 0; o >>= 1) s += __shfl_down(s, o, 64);
  __shared__ float wsh[4];
  int wid = t >> 6, lane = t & 63;
  if (lane == 0) wsh[wid] = s;
  __syncthreads();
  float tot = wsh[0] + wsh[1] + wsh[2] + wsh[3];
  float inv = 1.0f / fmaxf(sqrtf(tot), EPSV);
  float out = v * inv;
  if (strong) ds_dense[((size_t)k * KSEL + slot) * CDIM + t] = out;
  else        dw_dense[((size_t)k * 16 + (slot - KSEL)) * CDIM + t] = out;
}

// ---------------- K3b: cosm, per-row max, per-class sum ----------------
__global__ void k3b_loss(const float* __restrict__ dw_dense, const float* __restrict__ ds_dense,
                         const int* kwv, const int* ksv, const int* nwv, const int* nsv,
                         float* simsum, int* countk) {
  int k = blockIdx.x, t = threadIdx.x;
  __shared__ float wn[16 * CDIM];
  __shared__ float red[256];
  for (int i = t; i < 16 * CDIM; i += 256) wn[i] = dw_dense[(size_t)k * 16 * CDIM + i];
  __syncthreads();
  int ks_ = ksv[k], kw_ = kwv[k];
  bool ok = (nwv[k] > 0) && (nsv[k] > 0);
  float dots[16];
#pragma unroll
  for (int i = 0; i < 16; ++i) dots[i] = 0.0f;
  bool jv = ok && (t < ks_);
  if (jv) {
    const float4* sp = (const float4*)(ds_dense + ((size_t)k * KSEL + t) * CDIM);
    for (int c4 = 0; c4 < CDIM / 4; ++c4) {
      float4 v = sp[c4];
#pragma unroll
      for (int i = 0; i < 16; ++i) {
        float4 w = ((const float4*)(wn + i * CDIM))[c4];
        dots[i] = fmaf(v.x, w.x, dots[i]);
        dots[i] = fmaf(v.y, w.y, dots[i]);
        dots[i] = fmaf(v.z, w.z, dots[i]);
        dots[i] = fmaf(v.w, w.w, dots[i]);
      }
    }
  }
  float csum = 0.0f;
  for (int i = 0; i < 16; ++i) {
    red[t] = jv ? dots[i] : NEGV;
    __syncthreads();
    for (int s2 = 128; s2 > 0; s2 >>= 1) {
      if (t < s2) red[t] = fmaxf(red[t], red[t + s2]);
      __syncthreads();
    }
    if (t == 0 && i < kw_) csum += red[0];
    __syncthreads();
  }
  if (t == 0) { simsum[k] = ok ? csum : 0.0f; countk[k] = ok ? ks_ : 0; }
}

// ---------------- K4: memory bank update + loss ----------------
__global__ void k4_final(const float* __restrict__ mb, const float* __restrict__ wsum,
                         const int* __restrict__ nwv, const float* __restrict__ simsum,
                         const int* __restrict__ countk, float* out) {
  int k = blockIdx.x, t = threadIdx.x;
  float p = mb[k * CDIM + t];
  float o = p;
  int nw = nwv[k];
  if (nw > 0) {
    float mean = wsum[k * CDIM + t] / (float)nw;
    o = 0.99f * p + 0.01f * mean;
  }
  out[1 + k * CDIM + t] = o;
  if (k == 0 && t == 0) {
    float ss = 0.0f;
    int cc = 0;
    for (int q = 0; q < NCLS; ++q) { ss += simsum[q]; cc += countk[q]; }
    out[0] = (cc > 0) ? (1.0f - ss / (float)cc) : 0.0f;
  }
}

extern "C" void kernel_launch(void* const* d_in, const int* in_sizes, int n_in,
                              void* d_out, int out_size, void* d_ws, size_t ws_size,
                              hipStream_t stream) {
  const float* fw   = (const float*)d_in[0];
  const float* fs   = (const float*)d_in[1];
  const float* prob = (const float*)d_in[2];
  const float* mb   = (const float*)d_in[3];
  const int*   seg  = (const int*)d_in[4];
  const int*   ign  = (const int*)d_in[5];
  float* out = (float*)d_out;

  char* ws = (char*)d_ws;
  size_t off = 0;
  auto alloc = [&](size_t bytes) -> char* {
    char* p = ws + off;
    off = (off + bytes + 255) & ~(size_t)255;
    return p;
  };
  float*    pn       = (float*)alloc(NCLS * CDIM * 4);
  float*    wsum     = (float*)alloc(NCLS * CDIM * 4);
  int*      wcnt     = (int*)alloc(NCLS * 4);
  int*      scnt     = (int*)alloc(NCLS * 4);
  int*      idxw     = (int*)alloc(NCLS * 16 * 4);
  int*      idxs     = (int*)alloc(NCLS * KSEL * 4);
  int*      kwv      = (int*)alloc(NCLS * 4);
  int*      ksv      = (int*)alloc(NCLS * 4);
  int*      nwv      = (int*)alloc(NCLS * 4);
  int*      nsv      = (int*)alloc(NCLS * 4);
  float*    simsum   = (float*)alloc(NCLS * 4);
  int*      countk   = (int*)alloc(NCLS * 4);
  uint64_t* wkeys    = (uint64_t*)alloc((size_t)NCLS * CAP_W * 8);
  uint64_t* skeys    = (uint64_t*)alloc((size_t)NCLS * CAP_S * 8);
  uint64_t* psel     = (uint64_t*)alloc((size_t)NCLS * NPART * KSEL * 8);
  float*    dw_dense = (float*)alloc((size_t)NCLS * 16 * CDIM * 4);
  float*    ds_dense = (float*)alloc((size_t)NCLS * KSEL * CDIM * 4);
  float*    part     = (float*)alloc((size_t)NCC * NPIX * 4 * 4);  // 16.8 MB
  (void)in_sizes; (void)n_in; (void)out_size; (void)ws_size;

  k0_init<<<NCLS, 256, 0, stream>>>(mb, pn, wsum, wcnt, scnt);
  k1a_stream<<<dim3(NPIX / 1024, NCC), 256, 0, stream>>>(fw, fs, prob, seg, ign, pn,
                                                         part, wsum);
  k1b_combine<<<NPIX / 256, 256, 0, stream>>>(part, prob, seg, ign,
                                              wcnt, scnt, wkeys, skeys);
  k2_topk<<<NCLS * NPART + NCLS, 256, 0, stream>>>(wkeys, skeys, wcnt, scnt,
                                                   psel, idxw, kwv, nwv);
  k2m_merge<<<NCLS, 256, 0, stream>>>(psel, scnt, idxs, ksv, nsv);
  k3a_gather<<<dim3(KSEL + 16, NCLS), 256, 0, stream>>>(fw, fs, idxw, idxs, kwv, ksv,
                                                        dw_dense, ds_dense);
  k3b_loss<<<NCLS, 256, 0, stream>>>(dw_dense, ds_dense, kwv, ksv, nwv, nsv,
                                     simsum, countk);
  k4_final<<<NCLS, 256, 0, stream>>>(mb, wsum, nwv, simsum, countk, out);
}

// Round 3
// 433.552 us; speedup vs baseline: 2.0456x; 1.9937x over previous
//
#include <hip/hip_runtime.h>
#include <stdint.h>

#define NCLS  21
#define CDIM  256
#define HWSZ  16384
#define NPIX  131072
#define EPSV  1e-6f
#define NEGV  -1e30f
#define CAP_W 4096
#define CAP_S 16384
#define KSEL  256
#define NCC   8            // channel chunks in k1a
#define CCH   (CDIM/NCC)   // 32 channels per chunk
#define NPART 8            // strong top-k partitions per class
#define NBLK  (NPIX/1024)  // 128 pixel groups (1024 pixels each)

__device__ __forceinline__ uint64_t pack_key(float v, unsigned idx) {
  unsigned u = __float_as_uint(v);
  u = (u & 0x80000000u) ? ~u : (u | 0x80000000u);  // order-preserving map
  return ((uint64_t)(~u) << 32) | (uint64_t)idx;   // ascending key == descending value, tie -> low idx
}

// ---------------- K0: normalize prototypes, zero accumulators ----------------
__global__ void k0_init(const float* __restrict__ mb, float* pn, float* wsum) {
  int k = blockIdx.x, t = threadIdx.x;
  float v = mb[k * CDIM + t];
  float s = v * v;
  for (int o = 32; o > 0; o >>= 1) s += __shfl_down(s, o, 64);
  __shared__ float wsh[4];
  int wid = t >> 6, lane = t & 63;
  if (lane == 0) wsh[wid] = s;
  __syncthreads();
  float tot = wsh[0] + wsh[1] + wsh[2] + wsh[3];
  float inv = 1.0f / fmaxf(sqrtf(tot), EPSV);
  pn[k * CDIM + t] = v * inv;
  wsum[k * CDIM + t] = 0.0f;
}

// ---------------- K1a: streaming pass — float4 loads, partial dots, LDS wsum + counts ----------------
// grid: (NBLK, NCC). Each thread: 4 pixels, CCH channels.
__global__ void k1a_stream(const float* __restrict__ fw, const float* __restrict__ fs,
                           const float* __restrict__ prob, const int* __restrict__ seg,
                           const int* __restrict__ ign, const float* __restrict__ pn,
                           float* part, float* wsum, int* cnts) {
  __shared__ float pnT[CCH * NCLS];          // [c_local][k]
  __shared__ float wloc[NCLS * (CCH + 1)];   // [k][c_local], pad to break bank aliasing
  __shared__ int hs[NCLS], hw2[NCLS];
  int t = threadIdx.x;
  int pg = blockIdx.x;   // pixel group (1024 pixels)
  int cc = blockIdx.y;   // channel chunk
  int c0 = cc * CCH;
  for (int i = t; i < CCH * NCLS; i += 256) {
    int c = i / NCLS, k = i % NCLS;
    pnT[i] = pn[k * CDIM + c0 + c];
  }
  for (int i = t; i < NCLS * (CCH + 1); i += 256) wloc[i] = 0.0f;
  if (cc == 0) {
    for (int i = t; i < NCLS; i += 256) { hs[i] = 0; hw2[i] = 0; }
  }
  __syncthreads();

  int n0 = pg * 1024 + t * 4;
  int b = n0 >> 14, hw = n0 & (HWSZ - 1);
  int4   sg = *(const int4*)(seg + n0);
  int4   ig = *(const int4*)(ign + n0);
  float4 pr = *(const float4*)(prob + n0);
  bool v0 = (ig.x != 255), v1 = (ig.y != 255), v2 = (ig.z != 255), v3 = (ig.w != 255);
  bool cf0 = v0 && (pr.x > 0.95f);
  bool cf1 = v1 && (pr.y > 0.95f);
  bool cf2 = v2 && (pr.z > 0.95f);
  bool cf3 = v3 && (pr.w > 0.95f);
  if (cc == 0) {
    if (v0) atomicAdd(&hs[sg.x], 1);
    if (v1) atomicAdd(&hs[sg.y], 1);
    if (v2) atomicAdd(&hs[sg.z], 1);
    if (v3) atomicAdd(&hs[sg.w], 1);
    if (cf0) atomicAdd(&hw2[sg.x], 1);
    if (cf1) atomicAdd(&hw2[sg.y], 1);
    if (cf2) atomicAdd(&hw2[sg.z], 1);
    if (cf3) atomicAdd(&hw2[sg.w], 1);
  }

  const float* fwp = fw + ((size_t)b * CDIM + c0) * HWSZ + hw;
  const float* fsp = fs + ((size_t)b * CDIM + c0) * HWSZ + hw;

  float4 dw = {0,0,0,0}, nw = {0,0,0,0}, dsv = {0,0,0,0}, ns = {0,0,0,0};
#pragma unroll 4
  for (int cl = 0; cl < CCH; ++cl) {
    float4 a = *(const float4*)(fwp + (size_t)cl * HWSZ);
    float4 s = *(const float4*)(fsp + (size_t)cl * HWSZ);
    float p0 = pnT[cl * NCLS + sg.x];
    float p1 = pnT[cl * NCLS + sg.y];
    float p2 = pnT[cl * NCLS + sg.z];
    float p3 = pnT[cl * NCLS + sg.w];
    dw.x = fmaf(a.x, p0, dw.x); nw.x = fmaf(a.x, a.x, nw.x);
    dw.y = fmaf(a.y, p1, dw.y); nw.y = fmaf(a.y, a.y, nw.y);
    dw.z = fmaf(a.z, p2, dw.z); nw.z = fmaf(a.z, a.z, nw.z);
    dw.w = fmaf(a.w, p3, dw.w); nw.w = fmaf(a.w, a.w, nw.w);
    dsv.x = fmaf(s.x, p0, dsv.x); ns.x = fmaf(s.x, s.x, ns.x);
    dsv.y = fmaf(s.y, p1, dsv.y); ns.y = fmaf(s.y, s.y, ns.y);
    dsv.z = fmaf(s.z, p2, dsv.z); ns.z = fmaf(s.z, s.z, ns.z);
    dsv.w = fmaf(s.w, p3, dsv.w); ns.w = fmaf(s.w, s.w, ns.w);
    if (cf0) atomicAdd(&wloc[sg.x * (CCH + 1) + cl], a.x);
    if (cf1) atomicAdd(&wloc[sg.y * (CCH + 1) + cl], a.y);
    if (cf2) atomicAdd(&wloc[sg.z * (CCH + 1) + cl], a.z);
    if (cf3) atomicAdd(&wloc[sg.w * (CCH + 1) + cl], a.w);
  }
  float4* pp = (float4*)part + ((size_t)cc * NPIX + n0);
  pp[0] = make_float4(dw.x, nw.x, dsv.x, ns.x);
  pp[1] = make_float4(dw.y, nw.y, dsv.y, ns.y);
  pp[2] = make_float4(dw.z, nw.z, dsv.z, ns.z);
  pp[3] = make_float4(dw.w, nw.w, dsv.w, ns.w);

  __syncthreads();
  for (int i = t; i < NCLS * CCH; i += 256) {
    int k = i / CCH, cl = i % CCH;
    float v = wloc[k * (CCH + 1) + cl];
    if (v != 0.0f) atomicAdd(&wsum[k * CDIM + c0 + cl], v);
  }
  if (cc == 0) {
    for (int i = t; i < NCLS; i += 256) {
      cnts[pg * NCLS + i] = hs[i];
      cnts[NBLK * NCLS + pg * NCLS + i] = hw2[i];
    }
  }
}

// ---------------- KS: exclusive scan of per-block class counts ----------------
__global__ void ks_scan(const int* __restrict__ cnts, int* offs, int* scnt, int* wcnt) {
  __shared__ int L[2 * NBLK * NCLS];
  int t = threadIdx.x;
  for (int i = t; i < 2 * NBLK * NCLS; i += 256) L[i] = cnts[i];
  __syncthreads();
  if (t < 2 * NCLS) {
    int q = t % NCLS;
    int typ = t / NCLS;  // 0 strong, 1 weak
    int base = typ * NBLK * NCLS;
    int run = 0;
    for (int b2 = 0; b2 < NBLK; ++b2) {
      int v = L[base + b2 * NCLS + q];
      L[base + b2 * NCLS + q] = run;
      run += v;
    }
    if (typ == 0) scnt[q] = run; else wcnt[q] = run;
  }
  __syncthreads();
  for (int i = t; i < 2 * NBLK * NCLS; i += 256) offs[i] = L[i];
}

// ---------------- K1b: combine partials, compute sims, write keys at precomputed offsets ----------------
__global__ void k1b_write(const float* __restrict__ part, const float* __restrict__ prob,
                          const int* __restrict__ seg, const int* __restrict__ ign,
                          const int* __restrict__ offs, uint64_t* wkeys, uint64_t* skeys) {
  __shared__ int ls[NCLS], lw[NCLS];
  int t = threadIdx.x, pg = blockIdx.x;
  if (t < NCLS) {
    ls[t] = offs[pg * NCLS + t];
    lw[t] = offs[NBLK * NCLS + pg * NCLS + t];
  }
  __syncthreads();
  int n0 = pg * 1024 + t * 4;
  int4   sg = *(const int4*)(seg + n0);
  int4   ig = *(const int4*)(ign + n0);
  float4 pr = *(const float4*)(prob + n0);
  float dw[4] = {0,0,0,0}, nw[4] = {0,0,0,0}, ds[4] = {0,0,0,0}, ns[4] = {0,0,0,0};
#pragma unroll
  for (int cc = 0; cc < NCC; ++cc) {
    const float4* pp = (const float4*)part + ((size_t)cc * NPIX + n0);
#pragma unroll
    for (int i = 0; i < 4; ++i) {
      float4 v = pp[i];
      dw[i] += v.x; nw[i] += v.y; ds[i] += v.z; ns[i] += v.w;
    }
  }
  int   sga[4] = {sg.x, sg.y, sg.z, sg.w};
  int   iga[4] = {ig.x, ig.y, ig.z, ig.w};
  float pra[4] = {pr.x, pr.y, pr.z, pr.w};
#pragma unroll
  for (int i = 0; i < 4; ++i) {
    if (iga[i] != 255) {
      int q = sga[i];
      float sim_s = ds[i] / fmaxf(sqrtf(ns[i]), EPSV);
      int pos = atomicAdd(&ls[q], 1);
      if (pos < CAP_S) skeys[(size_t)q * CAP_S + pos] = pack_key(-sim_s, (unsigned)(n0 + i));
      if (pra[i] > 0.95f) {
        float sim_w = dw[i] / fmaxf(sqrtf(nw[i]), EPSV);
        int pw = atomicAdd(&lw[q], 1);
        if (pw < CAP_W) wkeys[(size_t)q * CAP_W + pw] = pack_key(sim_w, (unsigned)(n0 + i));
      }
    }
  }
}

// ---------------- top-256 select (cutoff-filtered bitonic), 256 threads ----------------
__device__ void select_topk(const uint64_t* __restrict__ list, int cnt,
                            uint64_t* T, uint64_t* P, int* pcnt, int* woff) {
  int t = threadIdx.x;
  T[t] = ~0ull;
  if (t == 0) *pcnt = 0;
  __syncthreads();
  for (int base = 0; base < cnt; base += 256) {
    uint64_t key = (base + t < cnt) ? list[base + t] : ~0ull;
    uint64_t cutoff = T[KSEL - 1];
    bool pred = key < cutoff;
    unsigned long long mask = __ballot(pred);
    int wid = t >> 6, lane = t & 63;
    if (lane == 0) woff[wid] = __popcll(mask);
    int prefix = __popcll(mask & ((1ull << lane) - 1ull));
    __syncthreads();
    int off = 0;
    for (int w2 = 0; w2 < wid; ++w2) off += woff[w2];
    int total = woff[0] + woff[1] + woff[2] + woff[3];
    int old = *pcnt;
    if (pred) P[old + off + prefix] = key;
    int newc = old + total;
    __syncthreads();
    if (t == 0) *pcnt = newc;
    bool last = (base + 256 >= cnt);
    if (newc >= KSEL || (last && newc > 0)) {
      for (int i2 = t; i2 < 2 * KSEL; i2 += 256)
        if (i2 >= newc) P[i2] = ~0ull;
      for (unsigned size = 2; size <= 2 * KSEL; size <<= 1) {
        for (unsigned stride = size >> 1; stride > 0; stride >>= 1) {
          __syncthreads();
          unsigned lo = stride - 1;
          unsigned i = (((unsigned)t & ~lo) << 1) | ((unsigned)t & lo);
          unsigned j = i | stride;
          uint64_t a = P[i], b = P[j];
          bool up = ((i & size) == 0);
          if ((a > b) == up) { P[i] = b; P[j] = a; }
        }
      }
      __syncthreads();
      uint64_t a = T[t], b = P[KSEL - 1 - t];
      T[t] = a < b ? a : b;
      for (unsigned stride = KSEL / 2; stride > 0; stride >>= 1) {
        __syncthreads();
        if (((unsigned)t & stride) == 0) {
          uint64_t x = T[t], y = T[t + stride];
          if (x > y) { T[t] = y; T[t + stride] = x; }
        }
      }
      __syncthreads();
      if (t == 0) *pcnt = 0;
      __syncthreads();
    } else {
      __syncthreads();
    }
  }
}

// ---------------- K2: weak top-16 (full) + strong top-256 (partitioned) ----------------
__global__ void k2_topk(const uint64_t* __restrict__ wkeys, const uint64_t* __restrict__ skeys,
                        const int* wcnt, const int* scnt,
                        uint64_t* psel, int* idxw, int* kwv, int* nwv) {
  __shared__ uint64_t T[KSEL];
  __shared__ uint64_t P[2 * KSEL];
  __shared__ int pcnt;
  __shared__ int woff[4];
  int bid = blockIdx.x, t = threadIdx.x;
  if (bid < NCLS * NPART) {
    int k = bid / NPART, p = bid % NPART;
    int cnt = min(scnt[k], CAP_S);
    int chunk = (cnt + NPART - 1) / NPART;
    int lo = p * chunk;
    int hi = min(lo + chunk, cnt);
    int c = hi > lo ? hi - lo : 0;
    select_topk(skeys + (size_t)k * CAP_S + lo, c, T, P, &pcnt, woff);
    psel[((size_t)k * NPART + p) * KSEL + t] = T[t];
  } else {
    int k = bid - NCLS * NPART;
    int cnt_total = wcnt[k];
    int cnt = min(cnt_total, CAP_W);
    select_topk(wkeys + (size_t)k * CAP_W, cnt, T, P, &pcnt, woff);
    if (t < 16) idxw[k * 16 + t] = (int)(unsigned)(T[t] & 0xFFFFFFFFull);
    if (t == 0) { nwv[k] = cnt_total; kwv[k] = min(cnt_total, 16); }
  }
}

// ---------------- K2m: merge 8 sorted partition results -> final strong top-256 ----------------
__global__ void k2m_merge(const uint64_t* __restrict__ psel, const int* scnt,
                          int* idxs, int* ksv, int* nsv) {
  int k = blockIdx.x, t = threadIdx.x;
  __shared__ uint64_t M[NPART * KSEL];  // 2048
  for (int i = t; i < NPART * KSEL; i += 256) M[i] = psel[(size_t)k * NPART * KSEL + i];
  for (unsigned size = 2; size <= NPART * KSEL; size <<= 1) {
    for (unsigned stride = size >> 1; stride > 0; stride >>= 1) {
      __syncthreads();
      for (unsigned q = t; q < NPART * KSEL / 2; q += 256) {
        unsigned lo = stride - 1;
        unsigned i = ((q & ~lo) << 1) | (q & lo);
        unsigned j = i | stride;
        uint64_t a = M[i], b = M[j];
        bool up = ((i & size) == 0);
        if ((a > b) == up) { M[i] = b; M[j] = a; }
      }
    }
  }
  __syncthreads();
  idxs[k * KSEL + t] = (int)(unsigned)(M[t] & 0xFFFFFFFFull);
  if (t == 0) { int c = scnt[k]; nsv[k] = c; ksv[k] = c < KSEL ? c : KSEL; }
}

// ---------------- K3a: gather + normalize selected vectors into dense buffers ----------------
__global__ void k3a_gather(const float* __restrict__ fw, const float* __restrict__ fs,
                           const int* __restrict__ idxw, const int* __restrict__ idxs,
                           const int* __restrict__ kwv, const int* __restrict__ ksv,
                           float* dw_dense, float* ds_dense) {
  int k = blockIdx.y;
  int slot = blockIdx.x;  // 0..255 strong, 256..271 weak
  int t = threadIdx.x;
  bool strong = slot < KSEL;
  float v = 0.0f;
  int n = 0;
  bool ok;
  if (strong) {
    ok = slot < ksv[k];
    if (ok) n = idxs[k * KSEL + slot];
  } else {
    int i = slot - KSEL;
    ok = i < kwv[k];
    int rank = i > 0 ? i - 1 : 0;  // ranks = max(arange(16)-1, 0)
    if (ok) n = idxw[k * 16 + rank];
  }
  if (ok) {
    int b = n >> 14, hw = n & (HWSZ - 1);
    const float* f = strong ? fs : fw;
    v = f[(size_t)(b * CDIM + t) * HWSZ + hw];
  }
  float s = v * v;
  for (int o = 32; o > 0; o >>= 1) s += __shfl_down(s, o, 64);
  __shared__ float wsh[4];
  int wid = t >> 6, lane = t & 63;
  if (lane == 0) wsh[wid] = s;
  __syncthreads();
  float tot = wsh[0] + wsh[1] + wsh[2] + wsh[3];
  float inv = 1.0f / fmaxf(sqrtf(tot), EPSV);
  float out = v * inv;
  if (strong) ds_dense[((size_t)k * KSEL + slot) * CDIM + t] = out;
  else        dw_dense[((size_t)k * 16 + (slot - KSEL)) * CDIM + t] = out;
}

// ---------------- K3b: cosm, per-row max, per-class sum ----------------
__global__ void k3b_loss(const float* __restrict__ dw_dense, const float* __restrict__ ds_dense,
                         const int* kwv, const int* ksv, const int* nwv, const int* nsv,
                         float* simsum, int* countk) {
  int k = blockIdx.x, t = threadIdx.x;
  int wid = t >> 6, lane = t & 63;
  __shared__ float wn[16 * CDIM];
  __shared__ float wred[4][16];
  for (int i = t; i < 16 * CDIM; i += 256) wn[i] = dw_dense[(size_t)k * 16 * CDIM + i];
  __syncthreads();
  int ks_ = ksv[k], kw_ = kwv[k];
  bool ok = (nwv[k] > 0) && (nsv[k] > 0);
  float dots[16];
#pragma unroll
  for (int i = 0; i < 16; ++i) dots[i] = 0.0f;
  bool jv = ok && (t < ks_);
  if (jv) {
    const float4* sp = (const float4*)(ds_dense + ((size_t)k * KSEL + t) * CDIM);
    for (int c4 = 0; c4 < CDIM / 4; ++c4) {
      float4 v = sp[c4];
#pragma unroll
      for (int i = 0; i < 16; ++i) {
        float4 w = ((const float4*)(wn + i * CDIM))[c4];
        dots[i] = fmaf(v.x, w.x, dots[i]);
        dots[i] = fmaf(v.y, w.y, dots[i]);
        dots[i] = fmaf(v.z, w.z, dots[i]);
        dots[i] = fmaf(v.w, w.w, dots[i]);
      }
    }
  }
#pragma unroll
  for (int i = 0; i < 16; ++i) {
    float v = jv ? dots[i] : NEGV;
    for (int o = 32; o > 0; o >>= 1) v = fmaxf(v, __shfl_down(v, o, 64));
    if (lane == 0) wred[wid][i] = v;
  }
  __syncthreads();
  if (t == 0) {
    float csum = 0.0f;
    for (int i = 0; i < kw_; ++i) {
      float m = fmaxf(fmaxf(wred[0][i], wred[1][i]), fmaxf(wred[2][i], wred[3][i]));
      csum += m;
    }
    simsum[k] = ok ? csum : 0.0f;
    countk[k] = ok ? ks_ : 0;
  }
}

// ---------------- K4: memory bank update + loss ----------------
__global__ void k4_final(const float* __restrict__ mb, const float* __restrict__ wsum,
                         const int* __restrict__ nwv, const float* __restrict__ simsum,
                         const int* __restrict__ countk, float* out) {
  int k = blockIdx.x, t = threadIdx.x;
  float p = mb[k * CDIM + t];
  float o = p;
  int nw = nwv[k];
  if (nw > 0) {
    float mean = wsum[k * CDIM + t] / (float)nw;
    o = 0.99f * p + 0.01f * mean;
  }
  out[1 + k * CDIM + t] = o;
  if (k == 0 && t == 0) {
    float ss = 0.0f;
    int cc = 0;
    for (int q = 0; q < NCLS; ++q) { ss += simsum[q]; cc += countk[q]; }
    out[0] = (cc > 0) ? (1.0f - ss / (float)cc) : 0.0f;
  }
}

extern "C" void kernel_launch(void* const* d_in, const int* in_sizes, int n_in,
                              void* d_out, int out_size, void* d_ws, size_t ws_size,
                              hipStream_t stream) {
  const float* fw   = (const float*)d_in[0];
  const float* fs   = (const float*)d_in[1];
  const float* prob = (const float*)d_in[2];
  const float* mb   = (const float*)d_in[3];
  const int*   seg  = (const int*)d_in[4];
  const int*   ign  = (const int*)d_in[5];
  float* out = (float*)d_out;

  char* ws = (char*)d_ws;
  size_t off = 0;
  auto alloc = [&](size_t bytes) -> char* {
    char* p = ws + off;
    off = (off + bytes + 255) & ~(size_t)255;
    return p;
  };
  float*    pn       = (float*)alloc(NCLS * CDIM * 4);
  float*    wsum     = (float*)alloc(NCLS * CDIM * 4);
  int*      wcnt     = (int*)alloc(NCLS * 4);
  int*      scnt     = (int*)alloc(NCLS * 4);
  int*      idxw     = (int*)alloc(NCLS * 16 * 4);
  int*      idxs     = (int*)alloc(NCLS * KSEL * 4);
  int*      kwv      = (int*)alloc(NCLS * 4);
  int*      ksv      = (int*)alloc(NCLS * 4);
  int*      nwv      = (int*)alloc(NCLS * 4);
  int*      nsv      = (int*)alloc(NCLS * 4);
  float*    simsum   = (float*)alloc(NCLS * 4);
  int*      countk   = (int*)alloc(NCLS * 4);
  int*      cnts     = (int*)alloc(2 * NBLK * NCLS * 4);
  int*      offs     = (int*)alloc(2 * NBLK * NCLS * 4);
  uint64_t* wkeys    = (uint64_t*)alloc((size_t)NCLS * CAP_W * 8);
  uint64_t* skeys    = (uint64_t*)alloc((size_t)NCLS * CAP_S * 8);
  uint64_t* psel     = (uint64_t*)alloc((size_t)NCLS * NPART * KSEL * 8);
  float*    dw_dense = (float*)alloc((size_t)NCLS * 16 * CDIM * 4);
  float*    ds_dense = (float*)alloc((size_t)NCLS * KSEL * CDIM * 4);
  float*    part     = (float*)alloc((size_t)NCC * NPIX * 4 * 4);  // 16.8 MB
  (void)in_sizes; (void)n_in; (void)out_size; (void)ws_size;

  k0_init<<<NCLS, 256, 0, stream>>>(mb, pn, wsum);
  k1a_stream<<<dim3(NBLK, NCC), 256, 0, stream>>>(fw, fs, prob, seg, ign, pn,
                                                  part, wsum, cnts);
  ks_scan<<<1, 256, 0, stream>>>(cnts, offs, scnt, wcnt);
  k1b_write<<<NBLK, 256, 0, stream>>>(part, prob, seg, ign, offs, wkeys, skeys);
  k2_topk<<<NCLS * NPART + NCLS, 256, 0, stream>>>(wkeys, skeys, wcnt, scnt,
                                                   psel, idxw, kwv, nwv);
  k2m_merge<<<NCLS, 256, 0, stream>>>(psel, scnt, idxs, ksv, nsv);
  k3a_gather<<<dim3(KSEL + 16, NCLS), 256, 0, stream>>>(fw, fs, idxw, idxs, kwv, ksv,
                                                        dw_dense, ds_dense);
  k3b_loss<<<NCLS, 256, 0, stream>>>(dw_dense, ds_dense, kwv, ksv, nwv, nsv,
                                     simsum, countk);
  k4_final<<<NCLS, 256, 0, stream>>>(mb, wsum, nwv, simsum, countk, out);
}